// Round 1
// baseline (616.485 us; speedup 1.0000x reference)
//
#include <hip/hip_runtime.h>

// FastSAM3DPromptEncoder: out[b,n,c] = pos_embed[0,c,z,y,x] + point_emb[labels[b,n],c]
// where (z,y,x) = clamp(trunc(points[b,n,:]), 0, 63).

constexpr int B_ = 32;
constexpr int N_ = 4096;
constexpr int C_ = 256;
constexpr int GD = 64;                 // grid dim (D=H=W=64)
constexpr int PTS = B_ * N_;           // 131072 points
constexpr int CELLS = GD * GD * GD;    // 262144 cells (stride between channels)

__global__ __launch_bounds__(256) void prompt_encoder_kernel(
    const float* __restrict__ points,   // [PTS, 3]
    const int*   __restrict__ labels,   // [PTS]
    const float* __restrict__ pos,      // [C, 64,64,64]
    const float* __restrict__ pemb,     // [2, C]
    float*       __restrict__ out)      // [PTS, C]
{
    const int t    = blockIdx.x * blockDim.x + threadIdx.x;
    const int p    = t >> 6;        // point index (one wave per point)
    const int lane = t & 63;
    const int c4   = lane << 2;     // 4 channels per lane
    if (p >= PTS) return;

    // All 64 lanes of the wave read the same 12B+4B -> broadcast loads, cheap.
    const float pz = points[p * 3 + 0];
    const float py = points[p * 3 + 1];
    const float px = points[p * 3 + 2];
    int zi = (int)pz; zi = min(max(zi, 0), GD - 1);
    int yi = (int)py; yi = min(max(yi, 0), GD - 1);
    int xi = (int)px; xi = min(max(xi, 0), GD - 1);
    const int cell = (zi << 12) + (yi << 6) + xi;

    const int lab = labels[p];
    const float4 te = *reinterpret_cast<const float4*>(pemb + lab * C_ + c4);

    // 4 gather loads, each 1 MiB apart in the channel dimension.
    const float* g = pos + cell;
    float4 r;
    r.x = g[(c4 + 0) * CELLS] + te.x;
    r.y = g[(c4 + 1) * CELLS] + te.y;
    r.z = g[(c4 + 2) * CELLS] + te.z;
    r.w = g[(c4 + 3) * CELLS] + te.w;

    *reinterpret_cast<float4*>(out + p * C_ + c4) = r;
}

extern "C" void kernel_launch(void* const* d_in, const int* in_sizes, int n_in,
                              void* d_out, int out_size, void* d_ws, size_t ws_size,
                              hipStream_t stream) {
    const float* points = (const float*)d_in[0];
    const int*   labels = (const int*)d_in[1];
    const float* pos    = (const float*)d_in[2];
    const float* pemb   = (const float*)d_in[3];
    float*       out    = (float*)d_out;

    const int threads = 256;
    const int total   = PTS * 64;                  // one wave (64 threads) per point
    const int blocks  = (total + threads - 1) / threads;
    prompt_encoder_kernel<<<blocks, threads, 0, stream>>>(points, labels, pos, pemb, out);
}

// Round 2
// 195.493 us; speedup vs baseline: 3.1535x; 3.1535x over previous
//
#include <hip/hip_runtime.h>

// FastSAM3DPromptEncoder: out[b,n,c] = pos_embed[0,c,z,y,x] + point_emb[labels[b,n],c]
// (z,y,x) = clamp(trunc(points[b,n,:]), 0, 63).
//
// Strategy: counting-sort points by 64-B-line key (z,y,x>>4) so points sharing
// a cache line are processed adjacently -> line fetched once instead of ~8x.

constexpr int B_ = 32;
constexpr int N_ = 4096;
constexpr int C_ = 256;
constexpr int GD = 64;
constexpr int PTS = B_ * N_;            // 131072
constexpr int CELLS = GD * GD * GD;     // 262144 (channel stride)
constexpr int NBINS = GD * GD * (GD / 16); // 16384 line keys

__device__ __forceinline__ int clamp63(float v) {
    int i = (int)v;
    return min(max(i, 0), GD - 1);
}

// ---- K0: zero the bin cursors' histogram ----
__global__ __launch_bounds__(256) void k_zero(unsigned* __restrict__ hist) {
    int t = blockIdx.x * blockDim.x + threadIdx.x;
    if (t < NBINS) hist[t] = 0u;
}

// ---- K1: histogram of line keys ----
__global__ __launch_bounds__(256) void k_hist(const float* __restrict__ points,
                                              unsigned* __restrict__ hist) {
    int p = blockIdx.x * blockDim.x + threadIdx.x;
    if (p >= PTS) return;
    int zi = clamp63(points[p * 3 + 0]);
    int yi = clamp63(points[p * 3 + 1]);
    int xi = clamp63(points[p * 3 + 2]);
    int key = (zi << 8) | (yi << 2) | (xi >> 4);
    atomicAdd(&hist[key], 1u);
}

// ---- K2: exclusive prefix sum over 16384 bins -> cursor (single block) ----
__global__ __launch_bounds__(1024) void k_scan(const unsigned* __restrict__ hist,
                                               unsigned* __restrict__ cursor) {
    __shared__ unsigned sums[1024];
    const int t = threadIdx.x;
    unsigned h[16];
    unsigned s = 0;
    #pragma unroll
    for (int i = 0; i < 16; ++i) { h[i] = hist[t * 16 + i]; s += h[i]; }
    sums[t] = s;
    __syncthreads();
    // Hillis-Steele inclusive scan over 1024 partials
    for (int off = 1; off < 1024; off <<= 1) {
        unsigned v = (t >= off) ? sums[t - off] : 0u;
        __syncthreads();
        sums[t] += v;
        __syncthreads();
    }
    unsigned run = (t > 0) ? sums[t - 1] : 0u;
    #pragma unroll
    for (int i = 0; i < 16; ++i) { cursor[t * 16 + i] = run; run += h[i]; }
}

// ---- K3: scatter points into sorted slots ----
__global__ __launch_bounds__(256) void k_scatter(const float* __restrict__ points,
                                                 const int* __restrict__ labels,
                                                 unsigned* __restrict__ cursor,
                                                 unsigned* __restrict__ rec_cell,
                                                 unsigned* __restrict__ rec_p) {
    int p = blockIdx.x * blockDim.x + threadIdx.x;
    if (p >= PTS) return;
    int zi = clamp63(points[p * 3 + 0]);
    int yi = clamp63(points[p * 3 + 1]);
    int xi = clamp63(points[p * 3 + 2]);
    int key  = (zi << 8) | (yi << 2) | (xi >> 4);
    int cell = (zi << 12) | (yi << 6) | xi;
    unsigned slot = atomicAdd(&cursor[key], 1u);
    rec_cell[slot] = (unsigned)cell | ((unsigned)labels[p] << 18);
    rec_p[slot]    = (unsigned)p;
}

// ---- K4: gather in sorted order. 16 slots/block, 4 slots/wave, lane = 4 channels ----
__global__ __launch_bounds__(256) void k_gather(const unsigned* __restrict__ rec_cell,
                                                const unsigned* __restrict__ rec_p,
                                                const float* __restrict__ pos,
                                                const float* __restrict__ pemb,
                                                float* __restrict__ out) {
    // XCD-chunked swizzle: contiguous slot ranges stay on one XCD's L2.
    const int nb  = gridDim.x;              // multiple of 8
    const int b   = blockIdx.x;
    const int swz = (b & 7) * (nb >> 3) + (b >> 3);
    const int wave = threadIdx.x >> 6;
    const int lane = threadIdx.x & 63;
    const int c4   = lane << 2;
    const int base = swz * 16 + wave * 4;

    #pragma unroll
    for (int i = 0; i < 4; ++i) {
        const int slot = base + i;
        const unsigned rc = rec_cell[slot];        // wave-uniform broadcast load
        const unsigned p  = rec_p[slot];
        const unsigned cell = rc & 0x3FFFFu;
        const unsigned lab  = rc >> 18;
        const float* g = pos + cell;
        const float4 te = *reinterpret_cast<const float4*>(pemb + lab * C_ + c4);
        float4 r;
        r.x = g[(size_t)(c4 + 0) * CELLS] + te.x;
        r.y = g[(size_t)(c4 + 1) * CELLS] + te.y;
        r.z = g[(size_t)(c4 + 2) * CELLS] + te.z;
        r.w = g[(size_t)(c4 + 3) * CELLS] + te.w;
        *reinterpret_cast<float4*>(out + (size_t)p * C_ + c4) = r;
    }
}

// ---- fallback (round-1 kernel) if ws is too small ----
__global__ __launch_bounds__(256) void k_naive(const float* __restrict__ points,
                                               const int* __restrict__ labels,
                                               const float* __restrict__ pos,
                                               const float* __restrict__ pemb,
                                               float* __restrict__ out) {
    const int t    = blockIdx.x * blockDim.x + threadIdx.x;
    const int p    = t >> 6;
    const int lane = t & 63;
    const int c4   = lane << 2;
    if (p >= PTS) return;
    int zi = clamp63(points[p * 3 + 0]);
    int yi = clamp63(points[p * 3 + 1]);
    int xi = clamp63(points[p * 3 + 2]);
    const int cell = (zi << 12) | (yi << 6) | xi;
    const int lab  = labels[p];
    const float4 te = *reinterpret_cast<const float4*>(pemb + lab * C_ + c4);
    const float* g = pos + cell;
    float4 r;
    r.x = g[(c4 + 0) * CELLS] + te.x;
    r.y = g[(c4 + 1) * CELLS] + te.y;
    r.z = g[(c4 + 2) * CELLS] + te.z;
    r.w = g[(c4 + 3) * CELLS] + te.w;
    *reinterpret_cast<float4*>(out + p * C_ + c4) = r;
}

extern "C" void kernel_launch(void* const* d_in, const int* in_sizes, int n_in,
                              void* d_out, int out_size, void* d_ws, size_t ws_size,
                              hipStream_t stream) {
    const float* points = (const float*)d_in[0];
    const int*   labels = (const int*)d_in[1];
    const float* pos    = (const float*)d_in[2];
    const float* pemb   = (const float*)d_in[3];
    float*       out    = (float*)d_out;

    // ws layout: hist[NBINS] | cursor[NBINS] | rec_cell[PTS] | rec_p[PTS]
    const size_t need = (size_t)(NBINS * 2 + PTS * 2) * sizeof(unsigned);
    if (ws_size < need) {
        const int total = PTS * 64;
        k_naive<<<(total + 255) / 256, 256, 0, stream>>>(points, labels, pos, pemb, out);
        return;
    }
    unsigned* hist     = (unsigned*)d_ws;
    unsigned* cursor   = hist + NBINS;
    unsigned* rec_cell = cursor + NBINS;
    unsigned* rec_p    = rec_cell + PTS;

    k_zero<<<(NBINS + 255) / 256, 256, 0, stream>>>(hist);
    k_hist<<<(PTS + 255) / 256, 256, 0, stream>>>(points, hist);
    k_scan<<<1, 1024, 0, stream>>>(hist, cursor);
    k_scatter<<<(PTS + 255) / 256, 256, 0, stream>>>(points, labels, cursor, rec_cell, rec_p);
    k_gather<<<PTS / 16, 256, 0, stream>>>(rec_cell, rec_p, pos, pemb, out);
}